// Round 3
// baseline (1479.262 us; speedup 1.0000x reference)
//
#include <hip/hip_runtime.h>

// SwinV2 window attention, fully fused: one block = one window (64 tokens x 192 dim).
// R4: 2 blocks/CU with K,V in LDS. LDS = 78,848 B: Qs(25,600) + Ks(25,600, reused as
// swizzled P tiles after kf loads) + Vt(24,576, XOR-swizzled stride-64) + nrm(3,072).
// No Xs: phase-1 A-frags read straight from global x with inline f32->bf16.
// q/k norms folded into softmax as rank-1 scale (no Q/K rewrite). All phases keep
// peak VGPR < 80 so __launch_bounds__(768,6) (cap 85) doesn't spill.

#define LDA 200   // Qs/Ks row stride (ushorts): 400B -> 2-way bank aliasing only

typedef __attribute__((ext_vector_type(4))) float floatx4;
typedef __attribute__((ext_vector_type(8))) short shortx8;
typedef __attribute__((ext_vector_type(4))) unsigned short ushortx4;

__device__ __forceinline__ unsigned short f2bf(float f) {
    union { float f; unsigned u; } v; v.f = f;
    return (unsigned short)((v.u + 0x7fffu + ((v.u >> 16) & 1u)) >> 16);  // RNE
}
__device__ __forceinline__ float bf2f(unsigned short s) {
    union { unsigned u; float f; } v; v.u = ((unsigned)s) << 16;
    return v.f;
}
// P-tile addressing inside the Ks overlay: 16 rows x 64 cols bf16 per wave,
// XOR-swizzled so b128 reads at row=c are ~2-way instead of 16-way.
__device__ __forceinline__ int ps_idx(int r, int col) {
    int byte = r * 128 + col * 2;
    byte ^= (r & 7) << 4;
    return byte >> 1;
}

// ---------------- prep: weights -> bf16, qkv bias concat ----------------
__global__ void prep_weights(const float* __restrict__ qkv_w,
                             const float* __restrict__ proj_w,
                             const float* __restrict__ q_bias,
                             const float* __restrict__ v_bias,
                             unsigned short* __restrict__ qkvw_bf,
                             unsigned short* __restrict__ projw_bf,
                             float* __restrict__ qkvb) {
    int stride = gridDim.x * blockDim.x;
    for (int i = blockIdx.x * blockDim.x + threadIdx.x; i < 110592 + 36864 + 576; i += stride) {
        if (i < 110592) {
            qkvw_bf[i] = f2bf(qkv_w[i]);
        } else if (i < 110592 + 36864) {
            projw_bf[i - 110592] = f2bf(proj_w[i - 110592]);
        } else {
            int j = i - 110592 - 36864;
            qkvb[j] = (j < 192) ? q_bias[j] : (j < 384 ? 0.f : v_bias[j - 384]);
        }
    }
}

// ---------------- prep: CPB MLP table, one wave per (pos, head) ----------------
__global__ void prep_cpb_tbl(const float* __restrict__ w1, const float* __restrict__ b1,
                             const float* __restrict__ w2, const float* __restrict__ rct,
                             float* __restrict__ tbls) {
    int wave = threadIdx.x >> 6, lane = threadIdx.x & 63;
    int pr = blockIdx.x * 4 + wave;                  // 225 positions x 6 heads = 1350
    if (pr >= 1350) return;
    int p = pr / 6, h = pr - p * 6;
    float c0 = rct[p * 2], c1 = rct[p * 2 + 1];
    float s = 0.f;
    #pragma unroll
    for (int it = 0; it < 8; ++it) {
        int j = lane + it * 64;
        float hv = fmaxf(0.f, c0 * w1[j * 2] + c1 * w1[j * 2 + 1] + b1[j]);
        s += hv * w2[h * 512 + j];
    }
    #pragma unroll
    for (int off = 32; off >= 1; off >>= 1) s += __shfl_xor(s, off);
    if (lane == 0) tbls[pr] = s;                     // [p][h]
}

// ---------------- prep: gather -> rpb[6][64][64] = 16*sigmoid ----------------
__global__ void prep_cpb_gather(const float* __restrict__ tbls, const int* __restrict__ rpi,
                                float* __restrict__ rpb) {
    int e = blockIdx.x * 256 + threadIdx.x;          // 6*64*64 = 24576
    if (e >= 24576) return;
    // rel_pos_index may arrive as int64 (little-endian pairs) or int32; rpi[1]==0 iff int64.
    int stride64 = (rpi[1] == 0) ? 2 : 1;
    int h = e >> 12, rc = e & 4095;
    int idx = rpi[rc * stride64];
    float t = tbls[idx * 6 + h];
    rpb[e] = 16.f / (1.f + __expf(-t));
}

// ---------------- main fused kernel ----------------
__global__ __launch_bounds__(768, 6) void win_attn(
    const float* __restrict__ x, const float* __restrict__ mask,
    const float* __restrict__ logit_scale,
    const unsigned short* __restrict__ qkvw, const unsigned short* __restrict__ projw,
    const float* __restrict__ qkvb, const float* __restrict__ projb,
    const float* __restrict__ rpb, float* __restrict__ out)
{
    __shared__ unsigned short Qs[64 * LDA];   // 25,600 B: q; phase-3+: attn output O
    __shared__ unsigned short Ks[64 * LDA];   // 25,600 B: k; after phase-3 kf loads: P tiles [12][1024]
    __shared__ unsigned short Vt[192 * 64];   // 24,576 B: V [dim][token], XOR-swizzled rows
    __shared__ float nrm[768];                //  3,072 B: [0..383]=rq (scale folded), [384..767]=rk

    const int tid  = threadIdx.x;
    const int b    = blockIdx.x;
    const int wave = tid >> 6, lane = tid & 63;
    const int c = lane & 15, qd = lane >> 4;       // MFMA lane coords: col / quad

    // ---- Phase 1: QKV GEMM (64x192)@(192x576); A-frags straight from global x ----
    // q -> Qs, k -> Ks (row-major, stride LDA); v -> Vt transposed ([dim][token], swizzled).
    {
        const float* xw = x + (size_t)b * 12288;
        for (int mh = 0; mh < 2; ++mh) {           // two 32-row halves keep af at 48 VGPRs
            shortx8 af[2][6];
            #pragma unroll
            for (int mi = 0; mi < 2; ++mi)
                #pragma unroll
                for (int ks = 0; ks < 6; ++ks) {
                    const float* xp = xw + (mh * 32 + mi * 16 + c) * 192 + ks * 32 + qd * 8;
                    float4 p0 = *(const float4*)xp;
                    float4 p1 = *(const float4*)(xp + 4);
                    shortx8 t;
                    t[0] = (short)f2bf(p0.x); t[1] = (short)f2bf(p0.y);
                    t[2] = (short)f2bf(p0.z); t[3] = (short)f2bf(p0.w);
                    t[4] = (short)f2bf(p1.x); t[5] = (short)f2bf(p1.y);
                    t[6] = (short)f2bf(p1.z); t[7] = (short)f2bf(p1.w);
                    af[mi][ks] = t;
                }
            for (int nti = 0; nti < 3; ++nti) {
                int nt = wave * 3 + nti;
                int gcol = nt * 16 + c;
                int part = nt / 12;                // 0=q, 1=k, 2=v
                int inner = gcol - part * 192;
                float bias = qkvb[gcol];
                const unsigned short* bp = qkvw + gcol * 192 + qd * 8;
                floatx4 acc[2];
                acc[0] = (floatx4){0.f, 0.f, 0.f, 0.f};
                acc[1] = (floatx4){0.f, 0.f, 0.f, 0.f};
                #pragma unroll
                for (int ks = 0; ks < 6; ++ks) {   // stream B one frag at a time: low VGPR
                    shortx8 b1 = *(const shortx8*)(bp + ks * 32);
                    acc[0] = __builtin_amdgcn_mfma_f32_16x16x32_bf16(af[0][ks], b1, acc[0], 0, 0, 0);
                    acc[1] = __builtin_amdgcn_mfma_f32_16x16x32_bf16(af[1][ks], b1, acc[1], 0, 0, 0);
                }
                #pragma unroll
                for (int mi = 0; mi < 2; ++mi) {
                    int row0 = (mh * 2 + mi) * 16 + qd * 4;  // C/D layout: row = qd*4+r, col = c
                    if (part == 2) {
                        ushortx4 pk;
                        #pragma unroll
                        for (int r = 0; r < 4; ++r) pk[r] = f2bf(acc[mi][r] + bias);
                        int byte = inner * 128 + row0 * 2;   // Vt[dim][token], 8B packed
                        byte ^= (inner & 7) << 4;            // swizzle (inner&7 == c&7)
                        *(ushortx4*)((char*)Vt + byte) = pk;
                    } else if (part == 1) {
                        #pragma unroll
                        for (int r = 0; r < 4; ++r)
                            Ks[(row0 + r) * LDA + inner] = f2bf(acc[mi][r] + bias);
                    } else {
                        #pragma unroll
                        for (int r = 0; r < 4; ++r)
                            Qs[(row0 + r) * LDA + inner] = f2bf(acc[mi][r] + bias);
                    }
                }
            }
        }
    }
    __syncthreads();

    // ---- Phase 2: norm scales only (no q/k rewrite). rq = exp(min(ls,ln100))/||q||, rk = 1/||k|| ----
    {
        int pqk = tid / 384, rem = tid - pqk * 384;  // 2 x 6 heads x 64 tokens = 768 exactly
        int h = rem >> 6, t = rem & 63;
        const unsigned short* p = (pqk == 0 ? Qs : Ks) + t * LDA + h * 32;
        shortx8 v0 = *(const shortx8*)(p),      v1 = *(const shortx8*)(p + 8),
                v2 = *(const shortx8*)(p + 16), v3 = *(const shortx8*)(p + 24);
        float s = 0.f;
        #pragma unroll
        for (int j = 0; j < 8; ++j) {
            float f0 = bf2f((unsigned short)v0[j]), f1 = bf2f((unsigned short)v1[j]);
            float f2 = bf2f((unsigned short)v2[j]), f3 = bf2f((unsigned short)v3[j]);
            s += f0 * f0 + f1 * f1 + f2 * f2 + f3 * f3;
        }
        float rn = 1.f / fmaxf(sqrtf(s), 1e-12f);
        if (pqk == 0) rn *= __expf(fminf(logit_scale[h], 4.605170185988091f));
        nrm[pqk * 384 + h * 64 + t] = rn;
    }
    __syncthreads();

    // ---- Phase 3: attention; 24 (head, m-tile) units = 2/wave, one head per wave ----
    {
        const float* maskw = mask + (size_t)(b & 63) * 4096;
        const int h = wave >> 1;
        const float* rpbh = rpb + h * 4096;
        shortx8 kf[4];                              // B frags: col = key token, k = head dim
        #pragma unroll
        for (int nt = 0; nt < 4; ++nt)
            kf[nt] = *(const shortx8*)&Ks[(nt * 16 + c) * LDA + h * 32 + qd * 8];
        float rkc[4];
        #pragma unroll
        for (int nt = 0; nt < 4; ++nt) rkc[nt] = nrm[384 + h * 64 + nt * 16 + c];
        __syncthreads();                            // ALL waves' kf loaded; Ks is now P scratch
        unsigned short* PsW = Ks + wave * 1024;     // 16x64 bf16 P tile per wave, swizzled
        #pragma unroll
        for (int mti = 0; mti < 2; ++mti) {
            int mt = (wave & 1) * 2 + mti;
            shortx8 qf = *(const shortx8*)&Qs[(mt * 16 + c) * LDA + h * 32 + qd * 8];
            floatx4 a[4];
            #pragma unroll
            for (int nt = 0; nt < 4; ++nt) {
                floatx4 z = (floatx4){0.f, 0.f, 0.f, 0.f};
                a[nt] = __builtin_amdgcn_mfma_f32_16x16x32_bf16(qf, kf[nt], z, 0, 0, 0);
            }
            float rqv[4];                           // per-row q scale (logit scale folded in)
            #pragma unroll
            for (int r = 0; r < 4; ++r) rqv[r] = nrm[h * 64 + mt * 16 + qd * 4 + r];
            // softmax over 64 cols of rows qd*4+r (16-lane groups share a row);
            // cosine normalization applied as rank-1 scaling rq[row]*rk[col]
            #pragma unroll
            for (int r = 0; r < 4; ++r) {
                int row = mt * 16 + qd * 4 + r;
                float vals[4], vmax = -1e30f;
                #pragma unroll
                for (int nt = 0; nt < 4; ++nt) {
                    int col = nt * 16 + c;
                    float v = a[nt][r] * rkc[nt] * rqv[r] + rpbh[row * 64 + col] + maskw[row * 64 + col];
                    vals[nt] = v; vmax = fmaxf(vmax, v);
                }
                #pragma unroll
                for (int off = 1; off < 16; off <<= 1)
                    vmax = fmaxf(vmax, __shfl_xor(vmax, off, 16));
                float ssum = 0.f;
                #pragma unroll
                for (int nt = 0; nt < 4; ++nt) {
                    float e = __expf(vals[nt] - vmax);
                    vals[nt] = e; ssum += e;
                }
                #pragma unroll
                for (int off = 1; off < 16; off <<= 1)
                    ssum += __shfl_xor(ssum, off, 16);
                float inv = 1.f / ssum;
                #pragma unroll
                for (int nt = 0; nt < 4; ++nt)
                    PsW[ps_idx(qd * 4 + r, nt * 16 + c)] = f2bf(vals[nt] * inv);
            }
            asm volatile("s_waitcnt lgkmcnt(0)" ::: "memory");  // P writes land before A-frag reads
            shortx8 pf[2];
            #pragma unroll
            for (int kn = 0; kn < 2; ++kn) {
                int byte = c * 128 + kn * 64 + qd * 16;
                byte ^= (c & 7) << 4;
                pf[kn] = *(const shortx8*)((const char*)PsW + byte);
            }
            shortx8 vf[2];                          // V frags loaded per nd: low VGPR pressure
            #pragma unroll
            for (int nd = 0; nd < 2; ++nd) {
                #pragma unroll
                for (int kn = 0; kn < 2; ++kn) {
                    int dim = h * 32 + nd * 16 + c;
                    int byte = dim * 128 + (kn * 32 + qd * 8) * 2;
                    byte ^= (c & 7) << 4;           // (dim&7) == (c&7)
                    vf[kn] = *(const shortx8*)((const char*)Vt + byte);
                }
                floatx4 o = (floatx4){0.f, 0.f, 0.f, 0.f};
                o = __builtin_amdgcn_mfma_f32_16x16x32_bf16(pf[0], vf[0], o, 0, 0, 0);
                o = __builtin_amdgcn_mfma_f32_16x16x32_bf16(pf[1], vf[1], o, 0, 0, 0);
                // O -> Qs rows (wave&1)*32+mti*16..: disjoint from every pending qf read
                // (same-h partner reads the other 32-row band; other heads use other columns).
                #pragma unroll
                for (int r = 0; r < 4; ++r)
                    Qs[(mt * 16 + qd * 4 + r) * LDA + h * 32 + nd * 16 + c] = f2bf(o[r]);
            }
        }
    }
    __syncthreads();

    // ---- Phase 4: proj GEMM (64x192)@(192x192) + bias -> out; 12 n-tiles = 1/wave ----
    {
        const int nt = wave;
        const unsigned short* bp = projw + (nt * 16 + c) * 192 + qd * 8;
        int gcol = nt * 16 + c;
        float bias = projb[gcol];
        float* outw = out + (size_t)b * 12288;
        #pragma unroll
        for (int mh = 0; mh < 2; ++mh) {
            floatx4 acc[2];
            acc[0] = (floatx4){0.f, 0.f, 0.f, 0.f};
            acc[1] = (floatx4){0.f, 0.f, 0.f, 0.f};
            #pragma unroll
            for (int ks = 0; ks < 6; ++ks) {        // stream A,B frags: low VGPR
                shortx8 b1 = *(const shortx8*)(bp + ks * 32);
                shortx8 a0 = *(const shortx8*)&Qs[((mh * 2) * 16 + c) * LDA + ks * 32 + qd * 8];
                shortx8 a1 = *(const shortx8*)&Qs[((mh * 2 + 1) * 16 + c) * LDA + ks * 32 + qd * 8];
                acc[0] = __builtin_amdgcn_mfma_f32_16x16x32_bf16(a0, b1, acc[0], 0, 0, 0);
                acc[1] = __builtin_amdgcn_mfma_f32_16x16x32_bf16(a1, b1, acc[1], 0, 0, 0);
            }
            #pragma unroll
            for (int mi = 0; mi < 2; ++mi)
                #pragma unroll
                for (int r = 0; r < 4; ++r)
                    outw[((mh * 2 + mi) * 16 + qd * 4 + r) * 192 + gcol] = acc[mi][r] + bias;
        }
    }
}

extern "C" void kernel_launch(void* const* d_in, const int* in_sizes, int n_in,
                              void* d_out, int out_size, void* d_ws, size_t ws_size,
                              hipStream_t stream) {
    const float* x           = (const float*)d_in[0];
    const float* mask        = (const float*)d_in[1];
    const float* qkv_w       = (const float*)d_in[2];
    const float* q_bias      = (const float*)d_in[3];
    const float* v_bias      = (const float*)d_in[4];
    const float* logit_scale = (const float*)d_in[5];
    const float* cpb_w1      = (const float*)d_in[6];
    const float* cpb_b1      = (const float*)d_in[7];
    const float* cpb_w2      = (const float*)d_in[8];
    const float* proj_w      = (const float*)d_in[9];
    const float* proj_b      = (const float*)d_in[10];
    const float* rct         = (const float*)d_in[11];
    const int*   rpi         = (const int*)d_in[12];

    char* ws = (char*)d_ws;
    unsigned short* qkvw_bf  = (unsigned short*)ws;             // 221,184 B
    unsigned short* projw_bf = (unsigned short*)(ws + 221184);  //  73,728 B
    float* qkvb = (float*)(ws + 294912);                        //   2,304 B
    float* rpb  = (float*)(ws + 297216);                        //  98,304 B
    float* tbls = (float*)(ws + 395520);                        //   5,400 B (total 400,920 B)

    prep_weights<<<64, 256, 0, stream>>>(qkv_w, proj_w, q_bias, v_bias, qkvw_bf, projw_bf, qkvb);
    prep_cpb_tbl<<<338, 256, 0, stream>>>(cpb_w1, cpb_b1, cpb_w2, rct, tbls);
    prep_cpb_gather<<<96, 256, 0, stream>>>(tbls, rpi, rpb);
    win_attn<<<4096, 768, 0, stream>>>(x, mask, logit_scale, qkvw_bf, projw_bf,
                                       qkvb, proj_b, rpb, (float*)d_out);
}

// Round 5
// 603.890 us; speedup vs baseline: 2.4496x; 2.4496x over previous
//
#include <hip/hip_runtime.h>

// SwinV2 window attention, fully fused: one block = one window (64 tokens x 192 dim).
// R5: 2 blocks/CU via LDS = 79,872 B with buffer overlays, NO global scratch, NO
// forced-low VGPR cap (R3/R4 lesson: (768,6) caused 40-VGPR spill allocation, 2.3GB
// of scratch traffic). Sequencing: Xs staged once; phase 1 = Q,K GEMM only; phase 3
// prologue loads K frags to regs then computes V GEMM into Ks (dead) as swizzled V^T;
// P tiles overlay Xs (dead after V GEMM); O overlays Qs. q/k norms folded into softmax
// as rank-1 scale. All swizzle/overlay math identical to the R4-verified kernel.

#define LDA 200   // Xs/Qs/Ks row stride (ushorts): 400B -> 2-way bank aliasing only

typedef __attribute__((ext_vector_type(4))) float floatx4;
typedef __attribute__((ext_vector_type(8))) short shortx8;
typedef __attribute__((ext_vector_type(4))) unsigned short ushortx4;

__device__ __forceinline__ unsigned short f2bf(float f) {
    union { float f; unsigned u; } v; v.f = f;
    return (unsigned short)((v.u + 0x7fffu + ((v.u >> 16) & 1u)) >> 16);  // RNE
}
__device__ __forceinline__ float bf2f(unsigned short s) {
    union { unsigned u; float f; } v; v.u = ((unsigned)s) << 16;
    return v.f;
}
// P-tile addressing (16 rows x 64 cols bf16 per wave, in the Xs overlay):
// XOR swizzle so b128 A-frag reads at row=c are spread across banks.
__device__ __forceinline__ int ps_idx(int r, int col) {
    int byte = r * 128 + col * 2;
    byte ^= (r & 7) << 4;
    return byte >> 1;
}

// ---------------- prep: weights -> bf16, qkv bias concat ----------------
__global__ void prep_weights(const float* __restrict__ qkv_w,
                             const float* __restrict__ proj_w,
                             const float* __restrict__ q_bias,
                             const float* __restrict__ v_bias,
                             unsigned short* __restrict__ qkvw_bf,
                             unsigned short* __restrict__ projw_bf,
                             float* __restrict__ qkvb) {
    int stride = gridDim.x * blockDim.x;
    for (int i = blockIdx.x * blockDim.x + threadIdx.x; i < 110592 + 36864 + 576; i += stride) {
        if (i < 110592) {
            qkvw_bf[i] = f2bf(qkv_w[i]);
        } else if (i < 110592 + 36864) {
            projw_bf[i - 110592] = f2bf(proj_w[i - 110592]);
        } else {
            int j = i - 110592 - 36864;
            qkvb[j] = (j < 192) ? q_bias[j] : (j < 384 ? 0.f : v_bias[j - 384]);
        }
    }
}

// ---------------- prep: CPB MLP table, one wave per (pos, head) ----------------
__global__ void prep_cpb_tbl(const float* __restrict__ w1, const float* __restrict__ b1,
                             const float* __restrict__ w2, const float* __restrict__ rct,
                             float* __restrict__ tbls) {
    int wave = threadIdx.x >> 6, lane = threadIdx.x & 63;
    int pr = blockIdx.x * 4 + wave;                  // 225 positions x 6 heads = 1350
    if (pr >= 1350) return;
    int p = pr / 6, h = pr - p * 6;
    float c0 = rct[p * 2], c1 = rct[p * 2 + 1];
    float s = 0.f;
    #pragma unroll
    for (int it = 0; it < 8; ++it) {
        int j = lane + it * 64;
        float hv = fmaxf(0.f, c0 * w1[j * 2] + c1 * w1[j * 2 + 1] + b1[j]);
        s += hv * w2[h * 512 + j];
    }
    #pragma unroll
    for (int off = 32; off >= 1; off >>= 1) s += __shfl_xor(s, off);
    if (lane == 0) tbls[pr] = s;                     // [p][h]
}

// ---------------- prep: gather -> rpb[6][64][64] = 16*sigmoid ----------------
__global__ void prep_cpb_gather(const float* __restrict__ tbls, const int* __restrict__ rpi,
                                float* __restrict__ rpb) {
    int e = blockIdx.x * 256 + threadIdx.x;          // 6*64*64 = 24576
    if (e >= 24576) return;
    // rel_pos_index may arrive as int64 (little-endian pairs) or int32; rpi[1]==0 iff int64.
    int stride64 = (rpi[1] == 0) ? 2 : 1;
    int h = e >> 12, rc = e & 4095;
    int idx = rpi[rc * stride64];
    float t = tbls[idx * 6 + h];
    rpb[e] = 16.f / (1.f + __expf(-t));
}

// ---------------- main fused kernel ----------------
__global__ __launch_bounds__(768, 3) void win_attn(
    const float* __restrict__ x, const float* __restrict__ mask,
    const float* __restrict__ logit_scale,
    const unsigned short* __restrict__ qkvw, const unsigned short* __restrict__ projw,
    const float* __restrict__ qkvb, const float* __restrict__ projb,
    const float* __restrict__ rpb, float* __restrict__ out)
{
    __shared__ unsigned short Xs[64 * LDA];   // 25,600 B: x bf16; ph3b+: P tiles [12][1024] swizzled
    __shared__ unsigned short Qs[64 * LDA];   // 25,600 B: q; ph3b+: attn output O (disjoint rows/cols)
    __shared__ unsigned short Ks[64 * LDA];   // 25,600 B: k; ph3a+: V^T [dim][token] XOR-swizzled
    __shared__ float nrm[768];                //  3,072 B: [0..383]=rq (scale folded), [384..767]=rk

    const int tid  = threadIdx.x;
    const int b    = blockIdx.x;
    const int wave = tid >> 6, lane = tid & 63;
    const int c = lane & 15, qd = lane >> 4;       // MFMA lane coords: col / quad

    // ---- Phase 0: stage x window (f32 -> bf16 LDS), once per block ----
    {
        const float4* xw = (const float4*)(x + (size_t)b * 12288);
        for (int i = tid; i < 3072; i += 768) {
            float4 v = xw[i];
            int token = i / 48, c4 = (i - token * 48) * 4;
            ushortx4 u = { f2bf(v.x), f2bf(v.y), f2bf(v.z), f2bf(v.w) };
            *(ushortx4*)&Xs[token * LDA + c4] = u;
        }
    }
    __syncthreads();

    // ---- Phase 1: Q,K GEMM (64x192)@(192x384), 24 n-tiles = 2/wave ----
    {
        for (int nti = 0; nti < 2; ++nti) {
            int nt = wave * 2 + nti;
            int gcol = nt * 16 + c;
            int part = nt / 12;                    // 0=q, 1=k
            int inner = gcol - part * 192;
            float bias = qkvb[gcol];
            const unsigned short* bp = qkvw + gcol * 192 + qd * 8;
            shortx8 bf[6];
            #pragma unroll
            for (int ks = 0; ks < 6; ++ks) bf[ks] = *(const shortx8*)(bp + ks * 32);
            #pragma unroll
            for (int mh = 0; mh < 2; ++mh) {       // 32-row halves: A re-read from LDS, low VGPR
                floatx4 acc[2];
                acc[0] = (floatx4){0.f, 0.f, 0.f, 0.f};
                acc[1] = (floatx4){0.f, 0.f, 0.f, 0.f};
                #pragma unroll
                for (int ks = 0; ks < 6; ++ks) {
                    shortx8 a0 = *(const shortx8*)&Xs[((mh * 2) * 16 + c) * LDA + ks * 32 + qd * 8];
                    shortx8 a1 = *(const shortx8*)&Xs[((mh * 2 + 1) * 16 + c) * LDA + ks * 32 + qd * 8];
                    acc[0] = __builtin_amdgcn_mfma_f32_16x16x32_bf16(a0, bf[ks], acc[0], 0, 0, 0);
                    acc[1] = __builtin_amdgcn_mfma_f32_16x16x32_bf16(a1, bf[ks], acc[1], 0, 0, 0);
                }
                unsigned short* dst = (part == 0) ? Qs : Ks;
                #pragma unroll
                for (int mi = 0; mi < 2; ++mi) {
                    int row0 = (mh * 2 + mi) * 16 + qd * 4;  // C/D: row = qd*4+r, col = c
                    #pragma unroll
                    for (int r = 0; r < 4; ++r)
                        dst[(row0 + r) * LDA + inner] = f2bf(acc[mi][r] + bias);
                }
            }
        }
    }
    __syncthreads();

    // ---- Phase 2: norm scales only. rq = exp(min(ls,ln100))/||q||, rk = 1/||k|| ----
    {
        int pqk = tid / 384, rem = tid - pqk * 384;  // 2 x 6 heads x 64 tokens = 768 exactly
        int h = rem >> 6, t = rem & 63;
        const unsigned short* p = (pqk == 0 ? Qs : Ks) + t * LDA + h * 32;
        shortx8 v0 = *(const shortx8*)(p),      v1 = *(const shortx8*)(p + 8),
                v2 = *(const shortx8*)(p + 16), v3 = *(const shortx8*)(p + 24);
        float s = 0.f;
        #pragma unroll
        for (int j = 0; j < 8; ++j) {
            float f0 = bf2f((unsigned short)v0[j]), f1 = bf2f((unsigned short)v1[j]);
            float f2 = bf2f((unsigned short)v2[j]), f3 = bf2f((unsigned short)v3[j]);
            s += f0 * f0 + f1 * f1 + f2 * f2 + f3 * f3;
        }
        float rn = 1.f / fmaxf(sqrtf(s), 1e-12f);
        if (pqk == 0) rn *= __expf(fminf(logit_scale[h], 4.605170185988091f));
        nrm[pqk * 384 + h * 64 + t] = rn;
    }
    __syncthreads();

    // ---- Phase 3a: K frags -> regs, then V GEMM into Ks overlay (V^T swizzled) ----
    const int h = wave >> 1;
    shortx8 kf[4];                              // B frags: col = key token, k = head dim
    #pragma unroll
    for (int nt = 0; nt < 4; ++nt)
        kf[nt] = *(const shortx8*)&Ks[(nt * 16 + c) * LDA + h * 32 + qd * 8];
    float rkc[4];
    #pragma unroll
    for (int nt = 0; nt < 4; ++nt) rkc[nt] = nrm[384 + h * 64 + nt * 16 + c];
    __syncthreads();                            // ALL waves' kf loaded; Ks is now V^T scratch
    {
        // V GEMM: 12 dim-tiles = 1/wave. A from Xs, B = Wv cols 384..575.
        int inner = wave * 16 + c;              // output dim 0..191
        float bias = qkvb[384 + inner];
        const unsigned short* bp = qkvw + (384 + inner) * 192 + qd * 8;
        shortx8 bf[6];
        #pragma unroll
        for (int ks = 0; ks < 6; ++ks) bf[ks] = *(const shortx8*)(bp + ks * 32);
        #pragma unroll
        for (int mh = 0; mh < 2; ++mh) {
            floatx4 acc[2];
            acc[0] = (floatx4){0.f, 0.f, 0.f, 0.f};
            acc[1] = (floatx4){0.f, 0.f, 0.f, 0.f};
            #pragma unroll
            for (int ks = 0; ks < 6; ++ks) {
                shortx8 a0 = *(const shortx8*)&Xs[((mh * 2) * 16 + c) * LDA + ks * 32 + qd * 8];
                shortx8 a1 = *(const shortx8*)&Xs[((mh * 2 + 1) * 16 + c) * LDA + ks * 32 + qd * 8];
                acc[0] = __builtin_amdgcn_mfma_f32_16x16x32_bf16(a0, bf[ks], acc[0], 0, 0, 0);
                acc[1] = __builtin_amdgcn_mfma_f32_16x16x32_bf16(a1, bf[ks], acc[1], 0, 0, 0);
            }
            #pragma unroll
            for (int mi = 0; mi < 2; ++mi) {
                int token0 = (mh * 2 + mi) * 16 + qd * 4;    // C/D: row = token, col = dim
                ushortx4 pk;
                #pragma unroll
                for (int r = 0; r < 4; ++r) pk[r] = f2bf(acc[mi][r] + bias);
                int byte = inner * 128 + token0 * 2;         // V^T[dim][token], 8B packed
                byte ^= (inner & 7) << 4;                    // swizzle (inner&7 == c&7)
                *(ushortx4*)((char*)Ks + byte) = pk;
            }
        }
    }
    __syncthreads();                            // V^T visible; Xs reads done -> Xs is P scratch

    // ---- Phase 3b: attention; 24 (head, m-tile) units = 2/wave ----
    {
        const float* maskw = mask + (size_t)(b & 63) * 4096;
        const float* rpbh = rpb + h * 4096;
        unsigned short* PsW = Xs + wave * 1024;  // 16x64 bf16 P tile per wave, swizzled
        #pragma unroll
        for (int mti = 0; mti < 2; ++mti) {
            int mt = (wave & 1) * 2 + mti;
            float rm[4][4];                      // rpb+mask prefetch (L2 latency overlaps MFMA)
            #pragma unroll
            for (int r = 0; r < 4; ++r) {
                int row = mt * 16 + qd * 4 + r;
                #pragma unroll
                for (int nt = 0; nt < 4; ++nt) {
                    int col = nt * 16 + c;
                    rm[r][nt] = rpbh[row * 64 + col] + maskw[row * 64 + col];
                }
            }
            shortx8 qf = *(const shortx8*)&Qs[(mt * 16 + c) * LDA + h * 32 + qd * 8];
            floatx4 a[4];
            #pragma unroll
            for (int nt = 0; nt < 4; ++nt) {
                floatx4 z = (floatx4){0.f, 0.f, 0.f, 0.f};
                a[nt] = __builtin_amdgcn_mfma_f32_16x16x32_bf16(qf, kf[nt], z, 0, 0, 0);
            }
            float rqv[4];                        // per-row q scale (logit scale folded in)
            #pragma unroll
            for (int r = 0; r < 4; ++r) rqv[r] = nrm[h * 64 + mt * 16 + qd * 4 + r];
            // softmax over 64 cols of rows qd*4+r (16-lane groups share a row);
            // cosine normalization applied as rank-1 scaling rq[row]*rk[col]
            #pragma unroll
            for (int r = 0; r < 4; ++r) {
                float vals[4], vmax = -1e30f;
                #pragma unroll
                for (int nt = 0; nt < 4; ++nt) {
                    float v = a[nt][r] * rkc[nt] * rqv[r] + rm[r][nt];
                    vals[nt] = v; vmax = fmaxf(vmax, v);
                }
                #pragma unroll
                for (int off = 1; off < 16; off <<= 1)
                    vmax = fmaxf(vmax, __shfl_xor(vmax, off, 16));
                float ssum = 0.f;
                #pragma unroll
                for (int nt = 0; nt < 4; ++nt) {
                    float e = __expf(vals[nt] - vmax);
                    vals[nt] = e; ssum += e;
                }
                #pragma unroll
                for (int off = 1; off < 16; off <<= 1)
                    ssum += __shfl_xor(ssum, off, 16);
                float inv = 1.f / ssum;
                #pragma unroll
                for (int nt = 0; nt < 4; ++nt)
                    PsW[ps_idx(qd * 4 + r, nt * 16 + c)] = f2bf(vals[nt] * inv);
            }
            asm volatile("s_waitcnt lgkmcnt(0)" ::: "memory");  // P writes land before A-frag reads
            shortx8 pf[2];
            #pragma unroll
            for (int kn = 0; kn < 2; ++kn) {
                int byte = c * 128 + kn * 64 + qd * 16;
                byte ^= (c & 7) << 4;
                pf[kn] = *(const shortx8*)((const char*)PsW + byte);
            }
            #pragma unroll
            for (int nd = 0; nd < 2; ++nd) {
                shortx8 vf[2];                   // V frags from Ks overlay (V^T swizzled)
                #pragma unroll
                for (int kn = 0; kn < 2; ++kn) {
                    int dim = h * 32 + nd * 16 + c;
                    int byte = dim * 128 + kn * 64 + qd * 16;
                    byte ^= (c & 7) << 4;        // (dim&7) == (c&7)
                    vf[kn] = *(const shortx8*)((const char*)Ks + byte);
                }
                floatx4 o = (floatx4){0.f, 0.f, 0.f, 0.f};
                o = __builtin_amdgcn_mfma_f32_16x16x32_bf16(pf[0], vf[0], o, 0, 0, 0);
                o = __builtin_amdgcn_mfma_f32_16x16x32_bf16(pf[1], vf[1], o, 0, 0, 0);
                // O -> Qs rows (wave&1)*32+mti*16..: disjoint from every pending qf read
                // (partner wave reads the other 32-row band; other heads use other columns).
                #pragma unroll
                for (int r = 0; r < 4; ++r)
                    Qs[(mt * 16 + qd * 4 + r) * LDA + h * 32 + nd * 16 + c] = f2bf(o[r]);
            }
        }
    }
    __syncthreads();

    // ---- Phase 4: proj GEMM (64x192)@(192x192) + bias -> out; 12 n-tiles = 1/wave ----
    {
        const int nt = wave;
        const unsigned short* bp = projw + (nt * 16 + c) * 192 + qd * 8;
        int gcol = nt * 16 + c;
        float bias = projb[gcol];
        float* outw = out + (size_t)b * 12288;
        #pragma unroll
        for (int mh = 0; mh < 2; ++mh) {
            floatx4 acc[2];
            acc[0] = (floatx4){0.f, 0.f, 0.f, 0.f};
            acc[1] = (floatx4){0.f, 0.f, 0.f, 0.f};
            #pragma unroll
            for (int ks = 0; ks < 6; ++ks) {        // stream A,B frags: low VGPR
                shortx8 b1 = *(const shortx8*)(bp + ks * 32);
                shortx8 a0 = *(const shortx8*)&Qs[((mh * 2) * 16 + c) * LDA + ks * 32 + qd * 8];
                shortx8 a1 = *(const shortx8*)&Qs[((mh * 2 + 1) * 16 + c) * LDA + ks * 32 + qd * 8];
                acc[0] = __builtin_amdgcn_mfma_f32_16x16x32_bf16(a0, b1, acc[0], 0, 0, 0);
                acc[1] = __builtin_amdgcn_mfma_f32_16x16x32_bf16(a1, b1, acc[1], 0, 0, 0);
            }
            #pragma unroll
            for (int mi = 0; mi < 2; ++mi)
                #pragma unroll
                for (int r = 0; r < 4; ++r)
                    outw[((mh * 2 + mi) * 16 + qd * 4 + r) * 192 + gcol] = acc[mi][r] + bias;
        }
    }
}

extern "C" void kernel_launch(void* const* d_in, const int* in_sizes, int n_in,
                              void* d_out, int out_size, void* d_ws, size_t ws_size,
                              hipStream_t stream) {
    const float* x           = (const float*)d_in[0];
    const float* mask        = (const float*)d_in[1];
    const float* qkv_w       = (const float*)d_in[2];
    const float* q_bias      = (const float*)d_in[3];
    const float* v_bias      = (const float*)d_in[4];
    const float* logit_scale = (const float*)d_in[5];
    const float* cpb_w1      = (const float*)d_in[6];
    const float* cpb_b1      = (const float*)d_in[7];
    const float* cpb_w2      = (const float*)d_in[8];
    const float* proj_w      = (const float*)d_in[9];
    const float* proj_b      = (const float*)d_in[10];
    const float* rct         = (const float*)d_in[11];
    const int*   rpi         = (const int*)d_in[12];

    char* ws = (char*)d_ws;
    unsigned short* qkvw_bf  = (unsigned short*)ws;             // 221,184 B
    unsigned short* projw_bf = (unsigned short*)(ws + 221184);  //  73,728 B
    float* qkvb = (float*)(ws + 294912);                        //   2,304 B
    float* rpb  = (float*)(ws + 297216);                        //  98,304 B
    float* tbls = (float*)(ws + 395520);                        //   5,400 B (total 400,920 B)

    prep_weights<<<64, 256, 0, stream>>>(qkv_w, proj_w, q_bias, v_bias, qkvw_bf, projw_bf, qkvb);
    prep_cpb_tbl<<<338, 256, 0, stream>>>(cpb_w1, cpb_b1, cpb_w2, rct, tbls);
    prep_cpb_gather<<<96, 256, 0, stream>>>(tbls, rpi, rpb);
    win_attn<<<4096, 768, 0, stream>>>(x, mask, logit_scale, qkvw_bf, projw_bf,
                                       qkvb, proj_b, rpb, (float*)d_out);
}